// Round 4
// baseline (604.662 us; speedup 1.0000x reference)
//
#include <hip/hip_runtime.h>
#include <math.h>

#define HEADS 4
#define DIM 64
#define FEAT 256   // HEADS*DIM

// ---------------------------------------------------------------------------
// CSR build: histogram over dst, hierarchical exclusive scan, scatter
// ---------------------------------------------------------------------------
__global__ __launch_bounds__(256) void hist_kernel(const int* __restrict__ dst,
                                                   int* __restrict__ deg, int E) {
    int i = blockIdx.x * blockDim.x + threadIdx.x;
    if (i < E) atomicAdd(&deg[dst[i]], 1);
}

// A: per-block (1024) exclusive scan; block total -> bsum[blockIdx]
__global__ __launch_bounds__(1024) void scan_block_kernel(const int* __restrict__ deg,
                                                          int* __restrict__ offs,
                                                          int* __restrict__ bsum, int n) {
    __shared__ int wsum[16];
    int tid = threadIdx.x, lane = tid & 63, w = tid >> 6;
    int i = blockIdx.x * 1024 + tid;
    int v = (i < n) ? deg[i] : 0;
    int x = v;
    #pragma unroll
    for (int off = 1; off < 64; off <<= 1) {
        int t = __shfl_up(x, off);
        if (lane >= off) x += t;
    }
    if (lane == 63) wsum[w] = x;
    __syncthreads();
    if (w == 0 && lane < 16) {
        int y = wsum[lane];
        #pragma unroll
        for (int off = 1; off < 16; off <<= 1) {
            int t = __shfl_up(y, off);
            if (lane >= off) y += t;
        }
        wsum[lane] = y;                    // inclusive scan of wave sums
    }
    __syncthreads();
    int wbase = (w == 0) ? 0 : wsum[w - 1];
    if (i < n) offs[i] = wbase + (x - v);  // block-local exclusive prefix
    if (tid == 0) bsum[blockIdx.x] = wsum[15];
}

// B: one wave scans the <=64 block sums; bofs[b]=exclusive, bofs[nb]=total
__global__ __launch_bounds__(64) void scan_small_kernel(const int* __restrict__ bsum,
                                                        int* __restrict__ bofs, int nb) {
    int lane = threadIdx.x;
    int v = (lane < nb) ? bsum[lane] : 0;
    int x = v;
    #pragma unroll
    for (int off = 1; off < 64; off <<= 1) {
        int t = __shfl_up(x, off);
        if (lane >= off) x += t;
    }
    if (lane < nb) bofs[lane] = x - v;
    if (lane == nb - 1) bofs[nb] = x;      // grand total
}

// C: add block offsets; offs[n] = total
__global__ __launch_bounds__(256) void scan_add_kernel(int* __restrict__ offs,
                                                       const int* __restrict__ bofs,
                                                       int n, int nb) {
    int i = blockIdx.x * blockDim.x + threadIdx.x;
    if (i < n)       offs[i] += bofs[i >> 10];
    else if (i == n) offs[n]  = bofs[nb];
}

__global__ __launch_bounds__(256) void scatter_kernel(const int* __restrict__ src,
                                                      const int* __restrict__ dst,
                                                      const int* __restrict__ offs,
                                                      int* __restrict__ cur,
                                                      int* __restrict__ esrc, int E) {
    int i = blockIdx.x * blockDim.x + threadIdx.x;
    if (i < E) {
        int d = dst[i];
        int pos = offs[d] + atomicAdd(&cur[d], 1);
        esrc[pos] = src[i];
    }
}

// ---------------------------------------------------------------------------
// fp32 GEMM: C[M,Nc] = A[M,K] @ B[K,Nc].  128x128 block tile, 8x8 per thread.
// (no fp32 MFMA on CDNA4 -> vector ALU; 16 KiB LDS)
// ---------------------------------------------------------------------------
#define GBM 128
#define GBN 128
#define GBK 16
__global__ __launch_bounds__(256) void gemm_f32(const float* __restrict__ A,
                                                const float* __restrict__ B,
                                                float* __restrict__ C,
                                                int M, int Nc, int K) {
    __shared__ float As[GBK][GBM];   // [k][m]
    __shared__ float Bs[GBK][GBN];   // [k][n]
    int tid = threadIdx.x;
    int m0 = blockIdx.x * GBM;
    int n0 = blockIdx.y * GBN;
    int tr = tid >> 4;   // 0..15 -> rows tr*8..tr*8+7
    int tc = tid & 15;   // 0..15 -> cols tc*8..tc*8+7

    float acc[8][8];
    #pragma unroll
    for (int i = 0; i < 8; ++i)
        #pragma unroll
        for (int j = 0; j < 8; ++j) acc[i][j] = 0.f;

    for (int k0 = 0; k0 < K; k0 += GBK) {
        // A tile: 128 rows x 16 cols; 2 float4 per thread; store transposed
        #pragma unroll
        for (int i = 0; i < 2; ++i) {
            int f  = tid * 2 + i;          // 0..511
            int r  = f >> 2;               // 0..127
            int c4 = (f & 3) << 2;         // 0,4,8,12
            int gr = m0 + r;
            float4 v = make_float4(0.f, 0.f, 0.f, 0.f);
            if (gr < M) v = *(const float4*)(A + (size_t)gr * K + k0 + c4);
            As[c4 + 0][r] = v.x; As[c4 + 1][r] = v.y;
            As[c4 + 2][r] = v.z; As[c4 + 3][r] = v.w;
        }
        // B tile: 16 rows x 128 cols; 2 float4 per thread, direct
        #pragma unroll
        for (int i = 0; i < 2; ++i) {
            int f  = tid * 2 + i;
            int r  = f >> 5;               // 0..15
            int c4 = (f & 31) << 2;        // 0..124
            float4 v = *(const float4*)(B + (size_t)(k0 + r) * Nc + n0 + c4);
            *(float4*)(&Bs[r][c4]) = v;
        }
        __syncthreads();
        #pragma unroll
        for (int k = 0; k < GBK; ++k) {
            float ra[8], rb[8];
            *(float4*)(ra)     = *(const float4*)(&As[k][tr * 8]);
            *(float4*)(ra + 4) = *(const float4*)(&As[k][tr * 8 + 4]);
            *(float4*)(rb)     = *(const float4*)(&Bs[k][tc * 8]);
            *(float4*)(rb + 4) = *(const float4*)(&Bs[k][tc * 8 + 4]);
            #pragma unroll
            for (int i = 0; i < 8; ++i)
                #pragma unroll
                for (int j = 0; j < 8; ++j)
                    acc[i][j] = fmaf(ra[i], rb[j], acc[i][j]);
        }
        __syncthreads();
    }
    #pragma unroll
    for (int i = 0; i < 8; ++i) {
        int gr = m0 + tr * 8 + i;
        if (gr < M) {
            float4 v0 = make_float4(acc[i][0], acc[i][1], acc[i][2], acc[i][3]);
            float4 v1 = make_float4(acc[i][4], acc[i][5], acc[i][6], acc[i][7]);
            *(float4*)(C + (size_t)gr * Nc + n0 + tc * 8)     = v0;
            *(float4*)(C + (size_t)gr * Nc + n0 + tc * 8 + 4) = v1;
        }
    }
}

// ---------------------------------------------------------------------------
// el[n,h] = sum_d feat[n,h,d]*al[h,d];  er likewise.  1 wave / node.
// Lane l owns dims 4l..4l+3 (head = l>>4); 16-lane group reduce per head.
// ---------------------------------------------------------------------------
__global__ __launch_bounds__(256) void eler_kernel(const float* __restrict__ feat,
                                                   const float* __restrict__ al,
                                                   const float* __restrict__ ar,
                                                   float* __restrict__ el,
                                                   float* __restrict__ er, int n_nodes) {
    int wid  = (blockIdx.x * blockDim.x + threadIdx.x) >> 6;
    int lane = threadIdx.x & 63;
    if (wid >= n_nodes) return;
    float4 f = *(const float4*)(feat + (size_t)wid * FEAT + lane * 4);
    float4 a = *(const float4*)(al + lane * 4);   // al is [H,D] = 256 contiguous
    float4 b = *(const float4*)(ar + lane * 4);
    float sl = f.x * a.x + f.y * a.y + f.z * a.z + f.w * a.w;
    float sr = f.x * b.x + f.y * b.y + f.z * b.z + f.w * b.w;
    #pragma unroll
    for (int off = 1; off < 16; off <<= 1) {      // reduce within 16-lane head group
        sl += __shfl_xor(sl, off);
        sr += __shfl_xor(sr, off);
    }
    if ((lane & 15) == 0) {
        el[(size_t)wid * 4 + (lane >> 4)] = sl;
        er[(size_t)wid * 4 + (lane >> 4)] = sr;
    }
}

// ---------------------------------------------------------------------------
// Per-dst-node online-softmax aggregation. 1 wave / node; lane l owns the 4
// contiguous dims 4l..4l+3 (head = l>>4). One dwordx4 gather per lane per
// edge; branchless online softmax (2 exp/lane/edge). No atomics. resid may
// alias out (row-exclusive). One-edge software pipeline hides gather latency.
// ---------------------------------------------------------------------------
__global__ __launch_bounds__(256) void aggregate_kernel(const float* __restrict__ feat,
                                                        const float* __restrict__ el,
                                                        const float* __restrict__ er,
                                                        const int* __restrict__ offs,
                                                        const int* __restrict__ esrc,
                                                        const float* resid,   // may be null / alias out
                                                        const float* __restrict__ bias,
                                                        float* out, int n_nodes) {
    int n    = (blockIdx.x * blockDim.x + threadIdx.x) >> 6;
    int lane = threadIdx.x & 63;
    if (n >= n_nodes) return;
    int hi = lane >> 4;                 // this lane's head, fixed

    int beg = offs[n], end = offs[n + 1];
    float4 er4 = *(const float4*)(er + (size_t)n * 4);
    float erv = (hi & 2) ? ((hi & 1) ? er4.w : er4.z)
                         : ((hi & 1) ? er4.y : er4.x);

    float m = -1e30f, s = 0.f;
    float4 acc = make_float4(0.f, 0.f, 0.f, 0.f);

    // prologue (every node has a self-loop, so beg < end)
    float4 el4_n = make_float4(0.f, 0.f, 0.f, 0.f);
    float4 fv_n  = make_float4(0.f, 0.f, 0.f, 0.f);
    if (beg < end) {
        int sn = esrc[beg];
        el4_n = *(const float4*)(el + (size_t)sn * 4);
        fv_n  = *(const float4*)(feat + (size_t)sn * FEAT + lane * 4);
    }

    for (int p = beg; p < end; ++p) {
        float4 el4 = el4_n;
        float4 fv  = fv_n;
        if (p + 1 < end) {              // issue next gathers before VALU body
            int sn = esrc[p + 1];
            el4_n = *(const float4*)(el + (size_t)sn * 4);
            fv_n  = *(const float4*)(feat + (size_t)sn * FEAT + lane * 4);
        }
        float elv = (hi & 2) ? ((hi & 1) ? el4.w : el4.z)
                             : ((hi & 1) ? el4.y : el4.x);
        float e  = elv + erv;
        float eh = e >= 0.f ? e : 0.2f * e;      // leaky_relu
        float mn = fmaxf(m, eh);
        float sc = __expf(m - mn);               // 0 on first iter (m=-1e30)
        float pr = __expf(eh - mn);
        s = s * sc + pr;
        acc.x = acc.x * sc + pr * fv.x;
        acc.y = acc.y * sc + pr * fv.y;
        acc.z = acc.z * sc + pr * fv.z;
        acc.w = acc.w * sc + pr * fv.w;
        m = mn;
    }

    float inv = 1.f / s;
    float4 r = make_float4(acc.x * inv, acc.y * inv, acc.z * inv, acc.w * inv);
    if (resid) {
        float4 rv = *(const float4*)(resid + (size_t)n * FEAT + lane * 4);
        r.x += rv.x; r.y += rv.y; r.z += rv.z; r.w += rv.w;
    }
    float4 bv = *(const float4*)(bias + lane * 4);
    r.x += bv.x; r.y += bv.y; r.z += bv.z; r.w += bv.w;
    *(float4*)(out + (size_t)n * FEAT + lane * 4) = r;
}

// ---------------------------------------------------------------------------
extern "C" void kernel_launch(void* const* d_in, const int* in_sizes, int n_in,
                              void* d_out, int out_size, void* d_ws, size_t ws_size,
                              hipStream_t stream) {
    const float* x   = (const float*)d_in[0];
    const float* w1  = (const float*)d_in[1];
    const float* b1  = (const float*)d_in[2];
    const float* al1 = (const float*)d_in[3];
    const float* ar1 = (const float*)d_in[4];
    const float* w2  = (const float*)d_in[5];
    const float* b2  = (const float*)d_in[6];
    const float* al2 = (const float*)d_in[7];
    const float* ar2 = (const float*)d_in[8];
    const int*   src = (const int*)d_in[9];
    const int*   dst = (const int*)d_in[10];
    int N = in_sizes[0] / DIM;    // 50000
    int E = in_sizes[9];          // 850000
    float* out = (float*)d_out;

    // workspace layout (~56 MB)
    float* feat = (float*)d_ws;                       // N*256
    float* el   = feat + (size_t)N * FEAT;            // N*4
    float* er   = el + (size_t)N * 4;                 // N*4
    int*   deg  = (int*)(er + (size_t)N * 4);         // N
    int*   cur  = deg + N;                            // N
    int*   offs = cur + N;                            // N+1
    int*   esrc = offs + (N + 1);                     // E
    int*   bsum = esrc + E;                           // 64
    int*   bofs = bsum + 64;                          // 65

    int nb = (N + 1023) / 1024;                       // 49 (<=64)

    // --- CSR build (once; shared by both layers) ---
    hipMemsetAsync(deg, 0, sizeof(int) * 2 * (size_t)N, stream);   // deg + cur
    hist_kernel<<<(E + 255) / 256, 256, 0, stream>>>(dst, deg, E);
    scan_block_kernel<<<nb, 1024, 0, stream>>>(deg, offs, bsum, N);
    scan_small_kernel<<<1, 64, 0, stream>>>(bsum, bofs, nb);
    scan_add_kernel<<<(N + 256) / 256, 256, 0, stream>>>(offs, bofs, N, nb);
    scatter_kernel<<<(E + 255) / 256, 256, 0, stream>>>(src, dst, offs, cur, esrc, E);

    dim3 ggrid((N + GBM - 1) / GBM, FEAT / GBN);
    int  ngrid = (N + 3) / 4;   // 4 waves (nodes) per 256-thread block

    // --- layer 1: feat = x@w1 ; out = aggregate + b1 ---
    gemm_f32<<<ggrid, 256, 0, stream>>>(x, w1, feat, N, FEAT, DIM);
    eler_kernel<<<ngrid, 256, 0, stream>>>(feat, al1, ar1, el, er, N);
    aggregate_kernel<<<ngrid, 256, 0, stream>>>(feat, el, er, offs, esrc,
                                                nullptr, b1, out, N);

    // --- layer 2: feat = out@w2 ; out = aggregate + out(residual) + b2 ---
    gemm_f32<<<ggrid, 256, 0, stream>>>(out, w2, feat, N, FEAT, FEAT);
    eler_kernel<<<ngrid, 256, 0, stream>>>(feat, al2, ar2, el, er, N);
    aggregate_kernel<<<ngrid, 256, 0, stream>>>(feat, el, er, offs, esrc,
                                                out, b2, out, N);
}

// Round 5
// 593.005 us; speedup vs baseline: 1.0197x; 1.0197x over previous
//
#include <hip/hip_runtime.h>
#include <math.h>

#define HEADS 4
#define DIM 64
#define FEAT 256   // HEADS*DIM

// ---------------------------------------------------------------------------
// CSR build: histogram over dst, hierarchical exclusive scan, scatter
// ---------------------------------------------------------------------------
__global__ __launch_bounds__(256) void hist_kernel(const int* __restrict__ dst,
                                                   int* __restrict__ deg, int E) {
    int i = blockIdx.x * blockDim.x + threadIdx.x;
    if (i < E) atomicAdd(&deg[dst[i]], 1);
}

// A: per-block (1024) exclusive scan; block total -> bsum[blockIdx]
__global__ __launch_bounds__(1024) void scan_block_kernel(const int* __restrict__ deg,
                                                          int* __restrict__ offs,
                                                          int* __restrict__ bsum, int n) {
    __shared__ int wsum[16];
    int tid = threadIdx.x, lane = tid & 63, w = tid >> 6;
    int i = blockIdx.x * 1024 + tid;
    int v = (i < n) ? deg[i] : 0;
    int x = v;
    #pragma unroll
    for (int off = 1; off < 64; off <<= 1) {
        int t = __shfl_up(x, off);
        if (lane >= off) x += t;
    }
    if (lane == 63) wsum[w] = x;
    __syncthreads();
    if (w == 0 && lane < 16) {
        int y = wsum[lane];
        #pragma unroll
        for (int off = 1; off < 16; off <<= 1) {
            int t = __shfl_up(y, off);
            if (lane >= off) y += t;
        }
        wsum[lane] = y;                    // inclusive scan of wave sums
    }
    __syncthreads();
    int wbase = (w == 0) ? 0 : wsum[w - 1];
    if (i < n) offs[i] = wbase + (x - v);  // block-local exclusive prefix
    if (tid == 0) bsum[blockIdx.x] = wsum[15];
}

// B: one wave scans the <=64 block sums; bofs[b]=exclusive, bofs[nb]=total
__global__ __launch_bounds__(64) void scan_small_kernel(const int* __restrict__ bsum,
                                                        int* __restrict__ bofs, int nb) {
    int lane = threadIdx.x;
    int v = (lane < nb) ? bsum[lane] : 0;
    int x = v;
    #pragma unroll
    for (int off = 1; off < 64; off <<= 1) {
        int t = __shfl_up(x, off);
        if (lane >= off) x += t;
    }
    if (lane < nb) bofs[lane] = x - v;
    if (lane == nb - 1) bofs[nb] = x;      // grand total
}

// C: add block offsets; offs[n] = total
__global__ __launch_bounds__(256) void scan_add_kernel(int* __restrict__ offs,
                                                       const int* __restrict__ bofs,
                                                       int n, int nb) {
    int i = blockIdx.x * blockDim.x + threadIdx.x;
    if (i < n)       offs[i] += bofs[i >> 10];
    else if (i == n) offs[n]  = bofs[nb];
}

__global__ __launch_bounds__(256) void scatter_kernel(const int* __restrict__ src,
                                                      const int* __restrict__ dst,
                                                      const int* __restrict__ offs,
                                                      int* __restrict__ cur,
                                                      int* __restrict__ esrc, int E) {
    int i = blockIdx.x * blockDim.x + threadIdx.x;
    if (i < E) {
        int d = dst[i];
        int pos = offs[d] + atomicAdd(&cur[d], 1);
        esrc[pos] = src[i];
    }
}

// ---------------------------------------------------------------------------
// fp32 GEMM: C[M,Nc] = A[M,K] @ B[K,Nc].  128x128 block tile, 8x8 per thread.
// ---------------------------------------------------------------------------
#define GBM 128
#define GBN 128
#define GBK 16
__global__ __launch_bounds__(256) void gemm_f32(const float* __restrict__ A,
                                                const float* __restrict__ B,
                                                float* __restrict__ C,
                                                int M, int Nc, int K) {
    __shared__ float As[GBK][GBM];   // [k][m]
    __shared__ float Bs[GBK][GBN];   // [k][n]
    int tid = threadIdx.x;
    int m0 = blockIdx.x * GBM;
    int n0 = blockIdx.y * GBN;
    int tr = tid >> 4;
    int tc = tid & 15;

    float acc[8][8];
    #pragma unroll
    for (int i = 0; i < 8; ++i)
        #pragma unroll
        for (int j = 0; j < 8; ++j) acc[i][j] = 0.f;

    for (int k0 = 0; k0 < K; k0 += GBK) {
        #pragma unroll
        for (int i = 0; i < 2; ++i) {
            int f  = tid * 2 + i;
            int r  = f >> 2;
            int c4 = (f & 3) << 2;
            int gr = m0 + r;
            float4 v = make_float4(0.f, 0.f, 0.f, 0.f);
            if (gr < M) v = *(const float4*)(A + (size_t)gr * K + k0 + c4);
            As[c4 + 0][r] = v.x; As[c4 + 1][r] = v.y;
            As[c4 + 2][r] = v.z; As[c4 + 3][r] = v.w;
        }
        #pragma unroll
        for (int i = 0; i < 2; ++i) {
            int f  = tid * 2 + i;
            int r  = f >> 5;
            int c4 = (f & 31) << 2;
            float4 v = *(const float4*)(B + (size_t)(k0 + r) * Nc + n0 + c4);
            *(float4*)(&Bs[r][c4]) = v;
        }
        __syncthreads();
        #pragma unroll
        for (int k = 0; k < GBK; ++k) {
            float ra[8], rb[8];
            *(float4*)(ra)     = *(const float4*)(&As[k][tr * 8]);
            *(float4*)(ra + 4) = *(const float4*)(&As[k][tr * 8 + 4]);
            *(float4*)(rb)     = *(const float4*)(&Bs[k][tc * 8]);
            *(float4*)(rb + 4) = *(const float4*)(&Bs[k][tc * 8 + 4]);
            #pragma unroll
            for (int i = 0; i < 8; ++i)
                #pragma unroll
                for (int j = 0; j < 8; ++j)
                    acc[i][j] = fmaf(ra[i], rb[j], acc[i][j]);
        }
        __syncthreads();
    }
    #pragma unroll
    for (int i = 0; i < 8; ++i) {
        int gr = m0 + tr * 8 + i;
        if (gr < M) {
            float4 v0 = make_float4(acc[i][0], acc[i][1], acc[i][2], acc[i][3]);
            float4 v1 = make_float4(acc[i][4], acc[i][5], acc[i][6], acc[i][7]);
            *(float4*)(C + (size_t)gr * Nc + n0 + tc * 8)     = v0;
            *(float4*)(C + (size_t)gr * Nc + n0 + tc * 8 + 4) = v1;
        }
    }
}

// ---------------------------------------------------------------------------
// el/er: lane l owns dims 4l..4l+3 (head = l>>4); 16-lane group reduce.
// ---------------------------------------------------------------------------
__global__ __launch_bounds__(256) void eler_kernel(const float* __restrict__ feat,
                                                   const float* __restrict__ al,
                                                   const float* __restrict__ ar,
                                                   float* __restrict__ el,
                                                   float* __restrict__ er, int n_nodes) {
    int wid  = (blockIdx.x * blockDim.x + threadIdx.x) >> 6;
    int lane = threadIdx.x & 63;
    if (wid >= n_nodes) return;
    float4 f = *(const float4*)(feat + (size_t)wid * FEAT + lane * 4);
    float4 a = *(const float4*)(al + lane * 4);
    float4 b = *(const float4*)(ar + lane * 4);
    float sl = f.x * a.x + f.y * a.y + f.z * a.z + f.w * a.w;
    float sr = f.x * b.x + f.y * b.y + f.z * b.z + f.w * b.w;
    #pragma unroll
    for (int off = 1; off < 16; off <<= 1) {
        sl += __shfl_xor(sl, off);
        sr += __shfl_xor(sr, off);
    }
    if ((lane & 15) == 0) {
        el[(size_t)wid * 4 + (lane >> 4)] = sl;
        er[(size_t)wid * 4 + (lane >> 4)] = sr;
    }
}

// ---------------------------------------------------------------------------
// Chunked per-dst aggregation. 1 wave/node. Per chunk of <=64 edges:
//   - 1 coalesced esrc load (lane = edge), el gathers (16B, L2-resident)
//   - wave-parallel chunk max/sum via shfl_xor; 8 exps/lane/chunk (was 2/edge)
//   - p published via per-wave LDS (same-wave write->read, in-order DS pipe)
//   - feat rows streamed in 4-edge groups, double-buffered (4KB/wave in flight)
// No atomics. resid may alias out (row-exclusive).
// ---------------------------------------------------------------------------
__global__ __launch_bounds__(256) void aggregate_kernel(const float* __restrict__ feat,
                                                        const float* __restrict__ el,
                                                        const float* __restrict__ er,
                                                        const int* __restrict__ offs,
                                                        const int* __restrict__ esrc,
                                                        const float* resid,   // may be null / alias out
                                                        const float* __restrict__ bias,
                                                        float* out, int n_nodes) {
    __shared__ float p_lds[4][256];
    int tid  = threadIdx.x;
    int wib  = tid >> 6;
    int lane = tid & 63;
    int n    = (blockIdx.x * blockDim.x + tid) >> 6;
    if (n >= n_nodes) return;
    int hi = lane >> 4;
    float* pw = p_lds[wib];

    int beg = offs[n], end = offs[n + 1];
    float4 er4 = *(const float4*)(er + (size_t)n * 4);

    float m0 = -1e30f, m1 = -1e30f, m2 = -1e30f, m3 = -1e30f;
    float s = 0.f;
    float4 acc = make_float4(0.f, 0.f, 0.f, 0.f);

    for (int cbeg = beg; cbeg < end; cbeg += 64) {
        int cnt = end - cbeg; if (cnt > 64) cnt = 64;
        int idx = cbeg + lane; if (idx >= end) idx = end - 1;   // pad with last edge
        int sn_l = esrc[idx];

        // e for this lane's edge, all 4 heads
        float4 el4 = *(const float4*)(el + (size_t)sn_l * 4);
        float e0 = el4.x + er4.x, e1 = el4.y + er4.y;
        float e2 = el4.z + er4.z, e3 = el4.w + er4.w;
        e0 = e0 >= 0.f ? e0 : 0.2f * e0;
        e1 = e1 >= 0.f ? e1 : 0.2f * e1;
        e2 = e2 >= 0.f ? e2 : 0.2f * e2;
        e3 = e3 >= 0.f ? e3 : 0.2f * e3;
        if (lane >= cnt) { e0 = e1 = e2 = e3 = -1e30f; }

        // chunk max per head (wave-wide)
        float c0 = e0, c1 = e1, c2 = e2, c3 = e3;
        #pragma unroll
        for (int off = 32; off; off >>= 1) {
            c0 = fmaxf(c0, __shfl_xor(c0, off));
            c1 = fmaxf(c1, __shfl_xor(c1, off));
            c2 = fmaxf(c2, __shfl_xor(c2, off));
            c3 = fmaxf(c3, __shfl_xor(c3, off));
        }
        float n0 = fmaxf(m0, c0), n1 = fmaxf(m1, c1);
        float n2 = fmaxf(m2, c2), n3 = fmaxf(m3, c3);
        float sc0 = __expf(m0 - n0), sc1 = __expf(m1 - n1);
        float sc2 = __expf(m2 - n2), sc3 = __expf(m3 - n3);
        float p0 = __expf(e0 - n0), p1 = __expf(e1 - n1);
        float p2 = __expf(e2 - n2), p3 = __expf(e3 - n3);   // 0 for pad lanes
        *(float4*)(&pw[lane * 4]) = make_float4(p0, p1, p2, p3);
        asm volatile("" ::: "memory");   // keep ds_write ordered before ds_reads

        // chunk sum per head (wave-wide)
        float t0 = p0, t1 = p1, t2 = p2, t3 = p3;
        #pragma unroll
        for (int off = 32; off; off >>= 1) {
            t0 += __shfl_xor(t0, off);
            t1 += __shfl_xor(t1, off);
            t2 += __shfl_xor(t2, off);
            t3 += __shfl_xor(t3, off);
        }
        float sc_own = (hi & 2) ? ((hi & 1) ? sc3 : sc2) : ((hi & 1) ? sc1 : sc0);
        float t_own  = (hi & 2) ? ((hi & 1) ? t3  : t2 ) : ((hi & 1) ? t1  : t0 );
        s = s * sc_own + t_own;
        acc.x *= sc_own; acc.y *= sc_own; acc.z *= sc_own; acc.w *= sc_own;
        m0 = n0; m1 = n1; m2 = n2; m3 = n3;

        // feat streaming: 4-edge groups, double-buffered named regs
        int ng = (cnt + 3) >> 2;
        float4 fA0, fA1, fA2, fA3, fB0, fB1, fB2, fB3;

        #define LOADG(F0, F1, F2, F3, G4)                                       \
            {                                                                   \
                int j0_ = (G4);                                                 \
                int s0_ = __shfl(sn_l, j0_),     s1_ = __shfl(sn_l, j0_ + 1);   \
                int s2_ = __shfl(sn_l, j0_ + 2), s3_ = __shfl(sn_l, j0_ + 3);   \
                F0 = *(const float4*)(feat + (size_t)s0_ * FEAT + lane * 4);    \
                F1 = *(const float4*)(feat + (size_t)s1_ * FEAT + lane * 4);    \
                F2 = *(const float4*)(feat + (size_t)s2_ * FEAT + lane * 4);    \
                F3 = *(const float4*)(feat + (size_t)s3_ * FEAT + lane * 4);    \
            }
        #define COMPG(F0, F1, F2, F3, G4)                                       \
            {                                                                   \
                int j0_ = (G4);                                                 \
                float q0_ = pw[j0_ * 4 + hi],       q1_ = pw[(j0_ + 1) * 4 + hi]; \
                float q2_ = pw[(j0_ + 2) * 4 + hi], q3_ = pw[(j0_ + 3) * 4 + hi]; \
                acc.x += q0_ * F0.x + q1_ * F1.x + q2_ * F2.x + q3_ * F3.x;     \
                acc.y += q0_ * F0.y + q1_ * F1.y + q2_ * F2.y + q3_ * F3.y;     \
                acc.z += q0_ * F0.z + q1_ * F1.z + q2_ * F2.z + q3_ * F3.z;     \
                acc.w += q0_ * F0.w + q1_ * F1.w + q2_ * F2.w + q3_ * F3.w;     \
            }

        LOADG(fA0, fA1, fA2, fA3, 0)
        int g = 0;
        while (true) {
            if (g + 1 < ng) LOADG(fB0, fB1, fB2, fB3, (g + 1) * 4)
            COMPG(fA0, fA1, fA2, fA3, g * 4)
            ++g; if (g >= ng) break;
            if (g + 1 < ng) LOADG(fA0, fA1, fA2, fA3, (g + 1) * 4)
            COMPG(fB0, fB1, fB2, fB3, g * 4)
            ++g; if (g >= ng) break;
        }
        #undef LOADG
        #undef COMPG
    }

    float inv = 1.f / s;
    float4 r = make_float4(acc.x * inv, acc.y * inv, acc.z * inv, acc.w * inv);
    if (resid) {
        float4 rv = *(const float4*)(resid + (size_t)n * FEAT + lane * 4);
        r.x += rv.x; r.y += rv.y; r.z += rv.z; r.w += rv.w;
    }
    float4 bv = *(const float4*)(bias + lane * 4);
    r.x += bv.x; r.y += bv.y; r.z += bv.z; r.w += bv.w;
    *(float4*)(out + (size_t)n * FEAT + lane * 4) = r;
}

// ---------------------------------------------------------------------------
extern "C" void kernel_launch(void* const* d_in, const int* in_sizes, int n_in,
                              void* d_out, int out_size, void* d_ws, size_t ws_size,
                              hipStream_t stream) {
    const float* x   = (const float*)d_in[0];
    const float* w1  = (const float*)d_in[1];
    const float* b1  = (const float*)d_in[2];
    const float* al1 = (const float*)d_in[3];
    const float* ar1 = (const float*)d_in[4];
    const float* w2  = (const float*)d_in[5];
    const float* b2  = (const float*)d_in[6];
    const float* al2 = (const float*)d_in[7];
    const float* ar2 = (const float*)d_in[8];
    const int*   src = (const int*)d_in[9];
    const int*   dst = (const int*)d_in[10];
    int N = in_sizes[0] / DIM;    // 50000
    int E = in_sizes[9];          // 850000
    float* out = (float*)d_out;

    // workspace layout (~56 MB)
    float* feat = (float*)d_ws;                       // N*256
    float* el   = feat + (size_t)N * FEAT;            // N*4
    float* er   = el + (size_t)N * 4;                 // N*4
    int*   deg  = (int*)(er + (size_t)N * 4);         // N
    int*   cur  = deg + N;                            // N
    int*   offs = cur + N;                            // N+1
    int*   esrc = offs + (N + 1);                     // E
    int*   bsum = esrc + E;                           // 64
    int*   bofs = bsum + 64;                          // 65

    int nb = (N + 1023) / 1024;                       // 49 (<=64)

    // --- CSR build (once; shared by both layers) ---
    hipMemsetAsync(deg, 0, sizeof(int) * 2 * (size_t)N, stream);   // deg + cur
    hist_kernel<<<(E + 255) / 256, 256, 0, stream>>>(dst, deg, E);
    scan_block_kernel<<<nb, 1024, 0, stream>>>(deg, offs, bsum, N);
    scan_small_kernel<<<1, 64, 0, stream>>>(bsum, bofs, nb);
    scan_add_kernel<<<(N + 256) / 256, 256, 0, stream>>>(offs, bofs, N, nb);
    scatter_kernel<<<(E + 255) / 256, 256, 0, stream>>>(src, dst, offs, cur, esrc, E);

    dim3 ggrid((N + GBM - 1) / GBM, FEAT / GBN);
    int  ngrid = (N + 3) / 4;   // 4 waves (nodes) per 256-thread block

    // --- layer 1: feat = x@w1 ; out = aggregate + b1 ---
    gemm_f32<<<ggrid, 256, 0, stream>>>(x, w1, feat, N, FEAT, DIM);
    eler_kernel<<<ngrid, 256, 0, stream>>>(feat, al1, ar1, el, er, N);
    aggregate_kernel<<<ngrid, 256, 0, stream>>>(feat, el, er, offs, esrc,
                                                nullptr, b1, out, N);

    // --- layer 2: feat = out@w2 ; out = aggregate + out(residual) + b2 ---
    gemm_f32<<<ggrid, 256, 0, stream>>>(out, w2, feat, N, FEAT, FEAT);
    eler_kernel<<<ngrid, 256, 0, stream>>>(feat, al2, ar2, el, er, N);
    aggregate_kernel<<<ngrid, 256, 0, stream>>>(feat, el, er, offs, esrc,
                                                out, b2, out, N);
}

// Round 12
// 458.811 us; speedup vs baseline: 1.3179x; 1.2925x over previous
//
#include <hip/hip_runtime.h>
#include <hip/hip_fp16.h>
#include <math.h>

#define HEADS 4
#define DIM 64
#define FEAT 256   // HEADS*DIM

__device__ inline float4 h4f(uint2 u) {
    __half2 a = __builtin_bit_cast(__half2, u.x);
    __half2 b = __builtin_bit_cast(__half2, u.y);
    float2 fa = __half22float2(a), fb = __half22float2(b);
    return make_float4(fa.x, fa.y, fb.x, fb.y);
}

// ---------------------------------------------------------------------------
// CSR build: histogram over dst, hierarchical exclusive scan, scatter
// ---------------------------------------------------------------------------
__global__ __launch_bounds__(256) void hist_kernel(const int* __restrict__ dst,
                                                   int* __restrict__ deg, int E) {
    int i = blockIdx.x * blockDim.x + threadIdx.x;
    if (i < E) atomicAdd(&deg[dst[i]], 1);
}

__global__ __launch_bounds__(1024) void scan_block_kernel(const int* __restrict__ deg,
                                                          int* __restrict__ offs,
                                                          int* __restrict__ bsum, int n) {
    __shared__ int wsum[16];
    int tid = threadIdx.x, lane = tid & 63, w = tid >> 6;
    int i = blockIdx.x * 1024 + tid;
    int v = (i < n) ? deg[i] : 0;
    int x = v;
    #pragma unroll
    for (int off = 1; off < 64; off <<= 1) {
        int t = __shfl_up(x, off);
        if (lane >= off) x += t;
    }
    if (lane == 63) wsum[w] = x;
    __syncthreads();
    if (w == 0 && lane < 16) {
        int y = wsum[lane];
        #pragma unroll
        for (int off = 1; off < 16; off <<= 1) {
            int t = __shfl_up(y, off);
            if (lane >= off) y += t;
        }
        wsum[lane] = y;
    }
    __syncthreads();
    int wbase = (w == 0) ? 0 : wsum[w - 1];
    if (i < n) offs[i] = wbase + (x - v);
    if (tid == 0) bsum[blockIdx.x] = wsum[15];
}

__global__ __launch_bounds__(64) void scan_small_kernel(const int* __restrict__ bsum,
                                                        int* __restrict__ bofs, int nb) {
    int lane = threadIdx.x;
    int v = (lane < nb) ? bsum[lane] : 0;
    int x = v;
    #pragma unroll
    for (int off = 1; off < 64; off <<= 1) {
        int t = __shfl_up(x, off);
        if (lane >= off) x += t;
    }
    if (lane < nb) bofs[lane] = x - v;
    if (lane == nb - 1) bofs[nb] = x;
}

__global__ __launch_bounds__(256) void scan_add_kernel(int* __restrict__ offs,
                                                       const int* __restrict__ bofs,
                                                       int n, int nb) {
    int i = blockIdx.x * blockDim.x + threadIdx.x;
    if (i < n)       offs[i] += bofs[i >> 10];
    else if (i == n) offs[n]  = bofs[nb];
}

__global__ __launch_bounds__(256) void scatter_kernel(const int* __restrict__ src,
                                                      const int* __restrict__ dst,
                                                      const int* __restrict__ offs,
                                                      int* __restrict__ cur,
                                                      int* __restrict__ esrc, int E) {
    int i = blockIdx.x * blockDim.x + threadIdx.x;
    if (i < E) {
        int d = dst[i];
        int pos = offs[d] + atomicAdd(&cur[d], 1);
        esrc[pos] = src[i];
    }
}

// ---------------------------------------------------------------------------
// fp32 GEMM -> fp16 output: C[M,Nc] = A[M,K] @ B[K,Nc].  128x128 tile, 8x8/thr.
// ---------------------------------------------------------------------------
#define GBM 128
#define GBN 128
#define GBK 16
__global__ __launch_bounds__(256) void gemm_f32h(const float* __restrict__ A,
                                                 const float* __restrict__ B,
                                                 __half* __restrict__ C,
                                                 int M, int Nc, int K) {
    __shared__ float As[GBK][GBM];   // [k][m]
    __shared__ float Bs[GBK][GBN];   // [k][n]
    int tid = threadIdx.x;
    int m0 = blockIdx.x * GBM;
    int n0 = blockIdx.y * GBN;
    int tr = tid >> 4;
    int tc = tid & 15;

    float acc[8][8];
    #pragma unroll
    for (int i = 0; i < 8; ++i)
        #pragma unroll
        for (int j = 0; j < 8; ++j) acc[i][j] = 0.f;

    for (int k0 = 0; k0 < K; k0 += GBK) {
        #pragma unroll
        for (int i = 0; i < 2; ++i) {
            int f  = tid * 2 + i;
            int r  = f >> 2;
            int c4 = (f & 3) << 2;
            int gr = m0 + r;
            float4 v = make_float4(0.f, 0.f, 0.f, 0.f);
            if (gr < M) v = *(const float4*)(A + (size_t)gr * K + k0 + c4);
            As[c4 + 0][r] = v.x; As[c4 + 1][r] = v.y;
            As[c4 + 2][r] = v.z; As[c4 + 3][r] = v.w;
        }
        #pragma unroll
        for (int i = 0; i < 2; ++i) {
            int f  = tid * 2 + i;
            int r  = f >> 5;
            int c4 = (f & 31) << 2;
            float4 v = *(const float4*)(B + (size_t)(k0 + r) * Nc + n0 + c4);
            *(float4*)(&Bs[r][c4]) = v;
        }
        __syncthreads();
        #pragma unroll
        for (int k = 0; k < GBK; ++k) {
            float ra[8], rb[8];
            *(float4*)(ra)     = *(const float4*)(&As[k][tr * 8]);
            *(float4*)(ra + 4) = *(const float4*)(&As[k][tr * 8 + 4]);
            *(float4*)(rb)     = *(const float4*)(&Bs[k][tc * 8]);
            *(float4*)(rb + 4) = *(const float4*)(&Bs[k][tc * 8 + 4]);
            #pragma unroll
            for (int i = 0; i < 8; ++i)
                #pragma unroll
                for (int j = 0; j < 8; ++j)
                    acc[i][j] = fmaf(ra[i], rb[j], acc[i][j]);
        }
        __syncthreads();
    }
    #pragma unroll
    for (int i = 0; i < 8; ++i) {
        int gr = m0 + tr * 8 + i;
        if (gr < M) {
            alignas(16) __half h[8];
            #pragma unroll
            for (int j = 0; j < 8; ++j) h[j] = __float2half_rn(acc[i][j]);
            *(uint4*)(C + (size_t)gr * Nc + n0 + tc * 8) = *(uint4*)h;  // 16B store
        }
    }
}

// ---------------------------------------------------------------------------
// el/er from fp16 feat: lane l owns dims 4l..4l+3 (head = l>>4).
// ---------------------------------------------------------------------------
__global__ __launch_bounds__(256) void eler_kernel(const __half* __restrict__ feat,
                                                   const float* __restrict__ al,
                                                   const float* __restrict__ ar,
                                                   float* __restrict__ el,
                                                   float* __restrict__ er, int n_nodes) {
    int wid  = (blockIdx.x * blockDim.x + threadIdx.x) >> 6;
    int lane = threadIdx.x & 63;
    if (wid >= n_nodes) return;
    float4 f = h4f(*(const uint2*)(feat + (size_t)wid * FEAT + lane * 4));
    float4 a = *(const float4*)(al + lane * 4);
    float4 b = *(const float4*)(ar + lane * 4);
    float sl = f.x * a.x + f.y * a.y + f.z * a.z + f.w * a.w;
    float sr = f.x * b.x + f.y * b.y + f.z * b.z + f.w * b.w;
    #pragma unroll
    for (int off = 1; off < 16; off <<= 1) {
        sl += __shfl_xor(sl, off);
        sr += __shfl_xor(sr, off);
    }
    if ((lane & 15) == 0) {
        el[(size_t)wid * 4 + (lane >> 4)] = sl;
        er[(size_t)wid * 4 + (lane >> 4)] = sr;
    }
}

// ---------------------------------------------------------------------------
// Chunked per-dst aggregation over fp16 feat (8B/lane/edge gathers).
// ---------------------------------------------------------------------------
__global__ __launch_bounds__(256) void aggregate_kernel(const __half* __restrict__ feat,
                                                        const float* __restrict__ el,
                                                        const float* __restrict__ er,
                                                        const int* __restrict__ offs,
                                                        const int* __restrict__ esrc,
                                                        const float* resid,   // may be null / alias out
                                                        const float* __restrict__ bias,
                                                        float* out, int n_nodes) {
    __shared__ float p_lds[4][256];
    int tid  = threadIdx.x;
    int wib  = tid >> 6;
    int lane = tid & 63;
    int n    = (blockIdx.x * blockDim.x + tid) >> 6;
    if (n >= n_nodes) return;
    int hi = lane >> 4;
    float* pw = p_lds[wib];

    int beg = offs[n], end = offs[n + 1];
    float4 er4 = *(const float4*)(er + (size_t)n * 4);

    float m0 = -1e30f, m1 = -1e30f, m2 = -1e30f, m3 = -1e30f;
    float s = 0.f;
    float4 acc = make_float4(0.f, 0.f, 0.f, 0.f);

    for (int cbeg = beg; cbeg < end; cbeg += 64) {
        int cnt = end - cbeg; if (cnt > 64) cnt = 64;
        int idx = cbeg + lane; if (idx >= end) idx = end - 1;   // pad with last edge
        int sn_l = esrc[idx];

        float4 el4 = *(const float4*)(el + (size_t)sn_l * 4);
        float e0 = el4.x + er4.x, e1 = el4.y + er4.y;
        float e2 = el4.z + er4.z, e3 = el4.w + er4.w;
        e0 = e0 >= 0.f ? e0 : 0.2f * e0;
        e1 = e1 >= 0.f ? e1 : 0.2f * e1;
        e2 = e2 >= 0.f ? e2 : 0.2f * e2;
        e3 = e3 >= 0.f ? e3 : 0.2f * e3;
        if (lane >= cnt) { e0 = e1 = e2 = e3 = -1e30f; }

        float c0 = e0, c1 = e1, c2 = e2, c3 = e3;
        #pragma unroll
        for (int off = 32; off; off >>= 1) {
            c0 = fmaxf(c0, __shfl_xor(c0, off));
            c1 = fmaxf(c1, __shfl_xor(c1, off));
            c2 = fmaxf(c2, __shfl_xor(c2, off));
            c3 = fmaxf(c3, __shfl_xor(c3, off));
        }
        float n0 = fmaxf(m0, c0), n1 = fmaxf(m1, c1);
        float n2 = fmaxf(m2, c2), n3 = fmaxf(m3, c3);
        float sc0 = __expf(m0 - n0), sc1 = __expf(m1 - n1);
        float sc2 = __expf(m2 - n2), sc3 = __expf(m3 - n3);
        float p0 = __expf(e0 - n0), p1 = __expf(e1 - n1);
        float p2 = __expf(e2 - n2), p3 = __expf(e3 - n3);   // 0 for pad lanes
        *(float4*)(&pw[lane * 4]) = make_float4(p0, p1, p2, p3);
        asm volatile("" ::: "memory");

        float t0 = p0, t1 = p1, t2 = p2, t3 = p3;
        #pragma unroll
        for (int off = 32; off; off >>= 1) {
            t0 += __shfl_xor(t0, off);
            t1 += __shfl_xor(t1, off);
            t2 += __shfl_xor(t2, off);
            t3 += __shfl_xor(t3, off);
        }
        float sc_own = (hi & 2) ? ((hi & 1) ? sc3 : sc2) : ((hi & 1) ? sc1 : sc0);
        float t_own  = (hi & 2) ? ((hi & 1) ? t3  : t2 ) : ((hi & 1) ? t1  : t0 );
        s = s * sc_own + t_own;
        acc.x *= sc_own; acc.y *= sc_own; acc.z *= sc_own; acc.w *= sc_own;
        m0 = n0; m1 = n1; m2 = n2; m3 = n3;

        // feat streaming: 4-edge groups, double-buffered named regs (fp16, 8B/lane)
        int ng = (cnt + 3) >> 2;
        uint2 fA0, fA1, fA2, fA3, fB0, fB1, fB2, fB3;

        #define LOADG(F0, F1, F2, F3, G4)                                       \
            {                                                                   \
                int j0_ = (G4);                                                 \
                int s0_ = __shfl(sn_l, j0_),     s1_ = __shfl(sn_l, j0_ + 1);   \
                int s2_ = __shfl(sn_l, j0_ + 2), s3_ = __shfl(sn_l, j0_ + 3);   \
                F0 = *(const uint2*)(feat + (size_t)s0_ * FEAT + lane * 4);     \
                F1 = *(const uint2*)(feat + (size_t)s1_ * FEAT + lane * 4);     \
                F2 = *(const uint2*)(feat + (size_t)s2_ * FEAT + lane * 4);     \
                F3 = *(const uint2*)(feat + (size_t)s3_ * FEAT + lane * 4);     \
            }
        #define COMPG(F0, F1, F2, F3, G4)                                       \
            {                                                                   \
                int j0_ = (G4);                                                 \
                float q0_ = pw[j0_ * 4 + hi],       q1_ = pw[(j0_ + 1) * 4 + hi]; \
                float q2_ = pw[(j0_ + 2) * 4 + hi], q3_ = pw[(j0_ + 3) * 4 + hi]; \
                float4 g0_ = h4f(F0), g1_ = h4f(F1), g2_ = h4f(F2), g3_ = h4f(F3); \
                acc.x += q0_ * g0_.x + q1_ * g1_.x + q2_ * g2_.x + q3_ * g3_.x; \
                acc.y += q0_ * g0_.y + q1_ * g1_.y + q2_ * g2_.y + q3_ * g3_.y; \
                acc.z += q0_ * g0_.z + q1_ * g1_.z + q2_ * g2_.z + q3_ * g3_.z; \
                acc.w += q0_ * g0_.w + q1_ * g1_.w + q2_ * g2_.w + q3_ * g3_.w; \
            }

        LOADG(fA0, fA1, fA2, fA3, 0)
        int g = 0;
        while (true) {
            if (g + 1 < ng) LOADG(fB0, fB1, fB2, fB3, (g + 1) * 4)
            COMPG(fA0, fA1, fA2, fA3, g * 4)
            ++g; if (g >= ng) break;
            if (g + 1 < ng) LOADG(fA0, fA1, fA2, fA3, (g + 1) * 4)
            COMPG(fB0, fB1, fB2, fB3, g * 4)
            ++g; if (g >= ng) break;
        }
        #undef LOADG
        #undef COMPG
    }

    float inv = 1.f / s;
    float4 r = make_float4(acc.x * inv, acc.y * inv, acc.z * inv, acc.w * inv);
    if (resid) {
        float4 rv = *(const float4*)(resid + (size_t)n * FEAT + lane * 4);
        r.x += rv.x; r.y += rv.y; r.z += rv.z; r.w += rv.w;
    }
    float4 bv = *(const float4*)(bias + lane * 4);
    r.x += bv.x; r.y += bv.y; r.z += bv.z; r.w += bv.w;
    *(float4*)(out + (size_t)n * FEAT + lane * 4) = r;
}

// ---------------------------------------------------------------------------
extern "C" void kernel_launch(void* const* d_in, const int* in_sizes, int n_in,
                              void* d_out, int out_size, void* d_ws, size_t ws_size,
                              hipStream_t stream) {
    const float* x   = (const float*)d_in[0];
    const float* w1  = (const float*)d_in[1];
    const float* b1  = (const float*)d_in[2];
    const float* al1 = (const float*)d_in[3];
    const float* ar1 = (const float*)d_in[4];
    const float* w2  = (const float*)d_in[5];
    const float* b2  = (const float*)d_in[6];
    const float* al2 = (const float*)d_in[7];
    const float* ar2 = (const float*)d_in[8];
    const int*   src = (const int*)d_in[9];
    const int*   dst = (const int*)d_in[10];
    int N = in_sizes[0] / DIM;    // 50000
    int E = in_sizes[9];          // 850000
    float* out = (float*)d_out;

    // workspace layout
    __half* featH = (__half*)d_ws;                    // N*256 fp16
    float*  el    = (float*)(featH + (size_t)N * FEAT);  // N*4
    float*  er    = el + (size_t)N * 4;               // N*4
    int*    deg   = (int*)(er + (size_t)N * 4);       // N
    int*    cur   = deg + N;                          // N
    int*    offs  = cur + N;                          // N+1
    int*    esrc  = offs + (N + 1);                   // E
    int*    bsum  = esrc + E;                         // 64
    int*    bofs  = bsum + 64;                        // 65

    int nb = (N + 1023) / 1024;                       // 49 (<=64)

    // --- CSR build (once; shared by both layers) ---
    hipMemsetAsync(deg, 0, sizeof(int) * 2 * (size_t)N, stream);   // deg + cur
    hist_kernel<<<(E + 255) / 256, 256, 0, stream>>>(dst, deg, E);
    scan_block_kernel<<<nb, 1024, 0, stream>>>(deg, offs, bsum, N);
    scan_small_kernel<<<1, 64, 0, stream>>>(bsum, bofs, nb);
    scan_add_kernel<<<(N + 256) / 256, 256, 0, stream>>>(offs, bofs, N, nb);
    scatter_kernel<<<(E + 255) / 256, 256, 0, stream>>>(src, dst, offs, cur, esrc, E);

    dim3 ggrid((N + GBM - 1) / GBM, FEAT / GBN);
    int  ngrid = (N + 3) / 4;   // 4 waves (nodes) per 256-thread block

    // --- layer 1: featH = fp16(x@w1) ; out = aggregate + b1 ---
    gemm_f32h<<<ggrid, 256, 0, stream>>>(x, w1, featH, N, FEAT, DIM);
    eler_kernel<<<ngrid, 256, 0, stream>>>(featH, al1, ar1, el, er, N);
    aggregate_kernel<<<ngrid, 256, 0, stream>>>(featH, el, er, offs, esrc,
                                                nullptr, b1, out, N);

    // --- layer 2: featH = fp16(out@w2) ; out = aggregate + out(residual) + b2 ---
    gemm_f32h<<<ggrid, 256, 0, stream>>>(out, w2, featH, N, FEAT, FEAT);
    eler_kernel<<<ngrid, 256, 0, stream>>>(featH, al2, ar2, el, er, N);
    aggregate_kernel<<<ngrid, 256, 0, stream>>>(featH, el, er, offs, esrc,
                                                out, b2, out, N);
}

// Round 13
// 399.017 us; speedup vs baseline: 1.5154x; 1.1499x over previous
//
#include <hip/hip_runtime.h>
#include <hip/hip_fp16.h>
#include <math.h>

#define HEADS 4
#define DIM 64
#define FEAT 256   // HEADS*DIM

typedef _Float16 half4v __attribute__((ext_vector_type(4)));
typedef float    f32x4  __attribute__((ext_vector_type(4)));

__device__ inline float4 h4f(uint2 u) {
    __half2 a = __builtin_bit_cast(__half2, u.x);
    __half2 b = __builtin_bit_cast(__half2, u.y);
    float2 fa = __half22float2(a), fb = __half22float2(b);
    return make_float4(fa.x, fa.y, fb.x, fb.y);
}

// ---------------------------------------------------------------------------
// CSR build: histogram over dst, hierarchical exclusive scan, scatter
// ---------------------------------------------------------------------------
__global__ __launch_bounds__(256) void hist_kernel(const int* __restrict__ dst,
                                                   int* __restrict__ deg, int E) {
    int i = blockIdx.x * blockDim.x + threadIdx.x;
    if (i < E) atomicAdd(&deg[dst[i]], 1);
}

__global__ __launch_bounds__(1024) void scan_block_kernel(const int* __restrict__ deg,
                                                          int* __restrict__ offs,
                                                          int* __restrict__ bsum, int n) {
    __shared__ int wsum[16];
    int tid = threadIdx.x, lane = tid & 63, w = tid >> 6;
    int i = blockIdx.x * 1024 + tid;
    int v = (i < n) ? deg[i] : 0;
    int x = v;
    #pragma unroll
    for (int off = 1; off < 64; off <<= 1) {
        int t = __shfl_up(x, off);
        if (lane >= off) x += t;
    }
    if (lane == 63) wsum[w] = x;
    __syncthreads();
    if (w == 0 && lane < 16) {
        int y = wsum[lane];
        #pragma unroll
        for (int off = 1; off < 16; off <<= 1) {
            int t = __shfl_up(y, off);
            if (lane >= off) y += t;
        }
        wsum[lane] = y;
    }
    __syncthreads();
    int wbase = (w == 0) ? 0 : wsum[w - 1];
    if (i < n) offs[i] = wbase + (x - v);
    if (tid == 0) bsum[blockIdx.x] = wsum[15];
}

__global__ __launch_bounds__(64) void scan_small_kernel(const int* __restrict__ bsum,
                                                        int* __restrict__ bofs, int nb) {
    int lane = threadIdx.x;
    int v = (lane < nb) ? bsum[lane] : 0;
    int x = v;
    #pragma unroll
    for (int off = 1; off < 64; off <<= 1) {
        int t = __shfl_up(x, off);
        if (lane >= off) x += t;
    }
    if (lane < nb) bofs[lane] = x - v;
    if (lane == nb - 1) bofs[nb] = x;
}

__global__ __launch_bounds__(256) void scan_add_kernel(int* __restrict__ offs,
                                                       const int* __restrict__ bofs,
                                                       int n, int nb) {
    int i = blockIdx.x * blockDim.x + threadIdx.x;
    if (i < n)       offs[i] += bofs[i >> 10];
    else if (i == n) offs[n]  = bofs[nb];
}

__global__ __launch_bounds__(256) void scatter_kernel(const int* __restrict__ src,
                                                      const int* __restrict__ dst,
                                                      const int* __restrict__ offs,
                                                      int* __restrict__ cur,
                                                      int* __restrict__ esrc, int E) {
    int i = blockIdx.x * blockDim.x + threadIdx.x;
    if (i < E) {
        int d = dst[i];
        int pos = offs[d] + atomicAdd(&cur[d], 1);
        esrc[pos] = src[i];
    }
}

// ---------------------------------------------------------------------------
// Weight transpose+convert: w[K][256] fp32 -> wt[256][K] fp16 (tiny)
// ---------------------------------------------------------------------------
__global__ __launch_bounds__(256) void wcvt_kernel(const float* __restrict__ w,
                                                   __half* __restrict__ wt, int K) {
    int id = blockIdx.x * 256 + threadIdx.x;
    if (id < K * 256) {
        int k = id >> 8, n = id & 255;
        wt[n * K + k] = __float2half_rn(w[id]);
    }
}

// ---------------------------------------------------------------------------
// MFMA fp16 GEMM: C[M][256] = fp16( A[M][K] (fp32, cast in staging) @ B )
// B pre-transposed fp16: Bt[256][K]. mfma_f32_16x16x16f16.
// Block tile 128x128, 4 waves (2x2), wave tile 64x64, K-step 32.
// Frag layouts (documented CDNA 16x16x16):
//   A: lane l holds A[l&15][(l>>4)*4 + j]
//   B: lane l holds B[(l>>4)*4 + j][l&15]
//   D: lane l reg r holds D[(l>>4)*4 + r][l&15]   (m89-verified)
// ---------------------------------------------------------------------------
#define TM 128
#define TN 128
#define KS 32
#define SA 40   // padded LDS stride (halves) -> de-conflicted frag reads
__global__ __launch_bounds__(256) void gemm_h(const float* __restrict__ A,
                                              const __half* __restrict__ Bt,
                                              __half* __restrict__ C,
                                              int M, int K) {
    __shared__ _Float16 As[TM * SA];
    __shared__ _Float16 Bs[TN * SA];
    int tid = threadIdx.x;
    int wid = tid >> 6, lane = tid & 63;
    int l15 = lane & 15, lg = lane >> 4;
    int wr = wid >> 1, wc = wid & 1;           // wave grid 2x2
    int m0 = blockIdx.x * TM;
    int n0 = blockIdx.y * TN;

    f32x4 acc[4][4];
    #pragma unroll
    for (int i = 0; i < 4; ++i)
        #pragma unroll
        for (int j = 0; j < 4; ++j) acc[i][j] = (f32x4){0.f, 0.f, 0.f, 0.f};

    for (int k0 = 0; k0 < K; k0 += KS) {
        // stage A: 128 rows x 32 k (fp32 -> fp16); 2 chunks of 8 halves / thread
        #pragma unroll
        for (int i = 0; i < 2; ++i) {
            int c = tid * 2 + i;               // 0..511
            int row = c >> 2;                  // 0..127
            int kc  = (c & 3) << 3;            // 0,8,16,24
            int gr  = m0 + row;
            float4 v0 = make_float4(0.f, 0.f, 0.f, 0.f);
            float4 v1 = make_float4(0.f, 0.f, 0.f, 0.f);
            if (gr < M) {
                const float* p = A + (size_t)gr * K + k0 + kc;
                v0 = *(const float4*)p;
                v1 = *(const float4*)(p + 4);
            }
            half4v h0 = {(_Float16)v0.x, (_Float16)v0.y, (_Float16)v0.z, (_Float16)v0.w};
            half4v h1 = {(_Float16)v1.x, (_Float16)v1.y, (_Float16)v1.z, (_Float16)v1.w};
            *(half4v*)(&As[row * SA + kc])     = h0;
            *(half4v*)(&As[row * SA + kc + 4]) = h1;
        }
        // stage B: 128 n-rows x 32 k (fp16 copy from Bt[n][k])
        #pragma unroll
        for (int i = 0; i < 2; ++i) {
            int c = tid * 2 + i;
            int n  = c >> 2;
            int kc = (c & 3) << 3;
            uint4 v = *(const uint4*)(Bt + (size_t)(n0 + n) * K + k0 + kc);
            *(uint4*)(&Bs[n * SA + kc]) = v;
        }
        __syncthreads();

        half4v a[4][2], b[4][2];
        #pragma unroll
        for (int ri = 0; ri < 4; ++ri)
            #pragma unroll
            for (int kh = 0; kh < 2; ++kh)
                a[ri][kh] = *(const half4v*)(&As[(wr * 64 + ri * 16 + l15) * SA + kh * 16 + lg * 4]);
        #pragma unroll
        for (int ci = 0; ci < 4; ++ci)
            #pragma unroll
            for (int kh = 0; kh < 2; ++kh)
                b[ci][kh] = *(const half4v*)(&Bs[(wc * 64 + ci * 16 + l15) * SA + kh * 16 + lg * 4]);

        #pragma unroll
        for (int kh = 0; kh < 2; ++kh)
            #pragma unroll
            for (int ri = 0; ri < 4; ++ri)
                #pragma unroll
                for (int ci = 0; ci < 4; ++ci)
                    acc[ri][ci] = __builtin_amdgcn_mfma_f32_16x16x16f16(
                        a[ri][kh], b[ci][kh], acc[ri][ci], 0, 0, 0);
        __syncthreads();
    }

    // epilogue: D[(lg*4+r)][l15] per 16x16 tile -> fp16 C
    #pragma unroll
    for (int ri = 0; ri < 4; ++ri) {
        #pragma unroll
        for (int r = 0; r < 4; ++r) {
            int grow = m0 + wr * 64 + ri * 16 + lg * 4 + r;
            if (grow < M) {
                #pragma unroll
                for (int ci = 0; ci < 4; ++ci) {
                    int gcol = n0 + wc * 64 + ci * 16 + l15;
                    C[(size_t)grow * FEAT + gcol] = __float2half_rn(acc[ri][ci][r]);
                }
            }
        }
    }
}

// ---------------------------------------------------------------------------
// el/er from fp16 feat: lane l owns dims 4l..4l+3 (head = l>>4).
// ---------------------------------------------------------------------------
__global__ __launch_bounds__(256) void eler_kernel(const __half* __restrict__ feat,
                                                   const float* __restrict__ al,
                                                   const float* __restrict__ ar,
                                                   float* __restrict__ el,
                                                   float* __restrict__ er, int n_nodes) {
    int wid  = (blockIdx.x * blockDim.x + threadIdx.x) >> 6;
    int lane = threadIdx.x & 63;
    if (wid >= n_nodes) return;
    float4 f = h4f(*(const uint2*)(feat + (size_t)wid * FEAT + lane * 4));
    float4 a = *(const float4*)(al + lane * 4);
    float4 b = *(const float4*)(ar + lane * 4);
    float sl = f.x * a.x + f.y * a.y + f.z * a.z + f.w * a.w;
    float sr = f.x * b.x + f.y * b.y + f.z * b.z + f.w * b.w;
    #pragma unroll
    for (int off = 1; off < 16; off <<= 1) {
        sl += __shfl_xor(sl, off);
        sr += __shfl_xor(sr, off);
    }
    if ((lane & 15) == 0) {
        el[(size_t)wid * 4 + (lane >> 4)] = sl;
        er[(size_t)wid * 4 + (lane >> 4)] = sr;
    }
}

// ---------------------------------------------------------------------------
// Chunked per-dst aggregation over fp16 feat (8B/lane/edge gathers). Unchanged
// from the verified R12 kernel.
// ---------------------------------------------------------------------------
__global__ __launch_bounds__(256) void aggregate_kernel(const __half* __restrict__ feat,
                                                        const float* __restrict__ el,
                                                        const float* __restrict__ er,
                                                        const int* __restrict__ offs,
                                                        const int* __restrict__ esrc,
                                                        const float* resid,   // may be null / alias out
                                                        const float* __restrict__ bias,
                                                        float* out, int n_nodes) {
    __shared__ float p_lds[4][256];
    int tid  = threadIdx.x;
    int wib  = tid >> 6;
    int lane = tid & 63;
    int n    = (blockIdx.x * blockDim.x + tid) >> 6;
    if (n >= n_nodes) return;
    int hi = lane >> 4;
    float* pw = p_lds[wib];

    int beg = offs[n], end = offs[n + 1];
    float4 er4 = *(const float4*)(er + (size_t)n * 4);

    float m0 = -1e30f, m1 = -1e30f, m2 = -1e30f, m3 = -1e30f;
    float s = 0.f;
    float4 acc = make_float4(0.f, 0.f, 0.f, 0.f);

    for (int cbeg = beg; cbeg < end; cbeg += 64) {
        int cnt = end - cbeg; if (cnt > 64) cnt = 64;
        int idx = cbeg + lane; if (idx >= end) idx = end - 1;   // pad with last edge
        int sn_l = esrc[idx];

        float4 el4 = *(const float4*)(el + (size_t)sn_l * 4);
        float e0 = el4.x + er4.x, e1 = el4.y + er4.y;
        float e2 = el4.z + er4.z, e3 = el4.w + er4.w;
        e0 = e0 >= 0.f ? e0 : 0.2f * e0;
        e1 = e1 >= 0.f ? e1 : 0.2f * e1;
        e2 = e2 >= 0.f ? e2 : 0.2f * e2;
        e3 = e3 >= 0.f ? e3 : 0.2f * e3;
        if (lane >= cnt) { e0 = e1 = e2 = e3 = -1e30f; }

        float c0 = e0, c1 = e1, c2 = e2, c3 = e3;
        #pragma unroll
        for (int off = 32; off; off >>= 1) {
            c0 = fmaxf(c0, __shfl_xor(c0, off));
            c1 = fmaxf(c1, __shfl_xor(c1, off));
            c2 = fmaxf(c2, __shfl_xor(c2, off));
            c3 = fmaxf(c3, __shfl_xor(c3, off));
        }
        float n0 = fmaxf(m0, c0), n1 = fmaxf(m1, c1);
        float n2 = fmaxf(m2, c2), n3 = fmaxf(m3, c3);
        float sc0 = __expf(m0 - n0), sc1 = __expf(m1 - n1);
        float sc2 = __expf(m2 - n2), sc3 = __expf(m3 - n3);
        float p0 = __expf(e0 - n0), p1 = __expf(e1 - n1);
        float p2 = __expf(e2 - n2), p3 = __expf(e3 - n3);   // 0 for pad lanes
        *(float4*)(&pw[lane * 4]) = make_float4(p0, p1, p2, p3);
        asm volatile("" ::: "memory");

        float t0 = p0, t1 = p1, t2 = p2, t3 = p3;
        #pragma unroll
        for (int off = 32; off; off >>= 1) {
            t0 += __shfl_xor(t0, off);
            t1 += __shfl_xor(t1, off);
            t2 += __shfl_xor(t2, off);
            t3 += __shfl_xor(t3, off);
        }
        float sc_own = (hi & 2) ? ((hi & 1) ? sc3 : sc2) : ((hi & 1) ? sc1 : sc0);
        float t_own  = (hi & 2) ? ((hi & 1) ? t3  : t2 ) : ((hi & 1) ? t1  : t0 );
        s = s * sc_own + t_own;
        acc.x *= sc_own; acc.y *= sc_own; acc.z *= sc_own; acc.w *= sc_own;
        m0 = n0; m1 = n1; m2 = n2; m3 = n3;

        int ng = (cnt + 3) >> 2;
        uint2 fA0, fA1, fA2, fA3, fB0, fB1, fB2, fB3;

        #define LOADG(F0, F1, F2, F3, G4)                                       \
            {                                                                   \
                int j0_ = (G4);                                                 \
                int s0_ = __shfl(sn_l, j0_),     s1_ = __shfl(sn_l, j0_ + 1);   \
                int s2_ = __shfl(sn_l, j0_ + 2), s3_ = __shfl(sn_l, j0_ + 3);   \
                F0 = *(const uint2*)(feat + (size_t)s0_ * FEAT + lane * 4);     \
                F1 = *(const uint2*)(feat + (size_t)s1_ * FEAT + lane * 4);     \
                F2 = *(const uint2*)(feat + (size_t)s2_ * FEAT + lane * 4);     \
                F3 = *(const uint2*)(feat + (size_t)s3_ * FEAT + lane * 4);     \
            }
        #define COMPG(F0, F1, F2, F3, G4)                                       \
            {                                                                   \
                int j0_ = (G4);                                                 \
                float q0_ = pw[j0_ * 4 + hi],       q1_ = pw[(j0_ + 1) * 4 + hi]; \
                float q2_ = pw[(j0_ + 2) * 4 + hi], q3_ = pw[(j0_ + 3) * 4 + hi]; \
                float4 g0_ = h4f(F0), g1_ = h4f(F1), g2_ = h4f(F2), g3_ = h4f(F3); \
                acc.x += q0_ * g0_.x + q1_ * g1_.x + q2_ * g2_.x + q3_ * g3_.x; \
                acc.y += q0_ * g0_.y + q1_ * g1_.y + q2_ * g2_.y + q3_ * g3_.y; \
                acc.z += q0_ * g0_.z + q1_ * g1_.z + q2_ * g2_.z + q3_ * g3_.z; \
                acc.w += q0_ * g0_.w + q1_ * g1_.w + q2_ * g2_.w + q3_ * g3_.w; \
            }

        LOADG(fA0, fA1, fA2, fA3, 0)
        int g = 0;
        while (true) {
            if (g + 1 < ng) LOADG(fB0, fB1, fB2, fB3, (g + 1) * 4)
            COMPG(fA0, fA1, fA2, fA3, g * 4)
            ++g; if (g >= ng) break;
            if (g + 1 < ng) LOADG(fA0, fA1, fA2, fA3, (g + 1) * 4)
            COMPG(fB0, fB1, fB2, fB3, g * 4)
            ++g; if (g >= ng) break;
        }
        #undef LOADG
        #undef COMPG
    }

    float inv = 1.f / s;
    float4 r = make_float4(acc.x * inv, acc.y * inv, acc.z * inv, acc.w * inv);
    if (resid) {
        float4 rv = *(const float4*)(resid + (size_t)n * FEAT + lane * 4);
        r.x += rv.x; r.y += rv.y; r.z += rv.z; r.w += rv.w;
    }
    float4 bv = *(const float4*)(bias + lane * 4);
    r.x += bv.x; r.y += bv.y; r.z += bv.z; r.w += bv.w;
    *(float4*)(out + (size_t)n * FEAT + lane * 4) = r;
}

// ---------------------------------------------------------------------------
extern "C" void kernel_launch(void* const* d_in, const int* in_sizes, int n_in,
                              void* d_out, int out_size, void* d_ws, size_t ws_size,
                              hipStream_t stream) {
    const float* x   = (const float*)d_in[0];
    const float* w1  = (const float*)d_in[1];
    const float* b1  = (const float*)d_in[2];
    const float* al1 = (const float*)d_in[3];
    const float* ar1 = (const float*)d_in[4];
    const float* w2  = (const float*)d_in[5];
    const float* b2  = (const float*)d_in[6];
    const float* al2 = (const float*)d_in[7];
    const float* ar2 = (const float*)d_in[8];
    const int*   src = (const int*)d_in[9];
    const int*   dst = (const int*)d_in[10];
    int N = in_sizes[0] / DIM;    // 50000
    int E = in_sizes[9];          // 850000
    float* out = (float*)d_out;

    // workspace layout (~33 MB, all vector-aligned)
    __half* featH = (__half*)d_ws;                       // N*256 halves
    __half* w1t   = featH + (size_t)N * FEAT;            // 256*64
    __half* w2t   = w1t + 256 * 64;                      // 256*256
    float*  el    = (float*)(w2t + 256 * 256);           // N*4
    float*  er    = el + (size_t)N * 4;                  // N*4
    int*    deg   = (int*)(er + (size_t)N * 4);          // N
    int*    cur   = deg + N;                             // N
    int*    offs  = cur + N;                             // N+1
    int*    esrc  = offs + (N + 1);                      // E
    int*    bsum  = esrc + E;                            // 64
    int*    bofs  = bsum + 64;                           // 65

    int nb = (N + 1023) / 1024;                          // 49 (<=64)

    // --- CSR build (once; shared by both layers) ---
    hipMemsetAsync(deg, 0, sizeof(int) * 2 * (size_t)N, stream);   // deg + cur
    hist_kernel<<<(E + 255) / 256, 256, 0, stream>>>(dst, deg, E);
    scan_block_kernel<<<nb, 1024, 0, stream>>>(deg, offs, bsum, N);
    scan_small_kernel<<<1, 64, 0, stream>>>(bsum, bofs, nb);
    scan_add_kernel<<<(N + 256) / 256, 256, 0, stream>>>(offs, bofs, N, nb);
    scatter_kernel<<<(E + 255) / 256, 256, 0, stream>>>(src, dst, offs, cur, esrc, E);

    // --- weight transpose+convert (tiny) ---
    wcvt_kernel<<<(64 * 256 + 255) / 256, 256, 0, stream>>>(w1, w1t, 64);
    wcvt_kernel<<<(256 * 256 + 255) / 256, 256, 0, stream>>>(w2, w2t, 256);

    dim3 ggrid((N + TM - 1) / TM, FEAT / TN);   // (391, 2)
    int  ngrid = (N + 3) / 4;   // 4 waves (nodes) per 256-thread block

    // --- layer 1: featH = fp16(x@w1) ; out = aggregate + b1 ---
    gemm_h<<<ggrid, 256, 0, stream>>>(x, w1t, featH, N, DIM);
    eler_kernel<<<ngrid, 256, 0, stream>>>(featH, al1, ar1, el, er, N);
    aggregate_kernel<<<ngrid, 256, 0, stream>>>(featH, el, er, offs, esrc,
                                                nullptr, b1, out, N);

    // --- layer 2: featH = fp16(out@w2) ; out = aggregate + out(residual) + b2 ---
    gemm_h<<<ggrid, 256, 0, stream>>>(out, w2t, featH, N, FEAT);
    eler_kernel<<<ngrid, 256, 0, stream>>>(featH, al2, ar2, el, er, N);
    aggregate_kernel<<<ngrid, 256, 0, stream>>>(featH, el, er, offs, esrc,
                                                out, b2, out, N);
}